// Round 1
// baseline (9812.742 us; speedup 1.0000x reference)
//
#include <hip/hip_runtime.h>
#include <float.h>

#define DECAY 0.99f
#define OMD   0.01f
#define EPSF  1e-6f

constexpr int Bb = 8, Ss = 8192, Dd = 256, Kk = 2048;
constexpr int Nn = Bb * Ss;                 // 65536 rows

// ---- output layout (floats) ----
constexpr long OUT_QUANT = 0;                         // 16777216
constexpr long OUT_IND   = (long)Nn * Dd;             // 16777216
constexpr long OUT_NCS   = OUT_IND + Nn;              // 16842752
constexpr long OUT_NEA   = OUT_NCS + Kk;              // 16844800
constexpr long OUT_NE    = OUT_NEA + (long)Kk * Dd;   // 17369088

// ---- workspace layout (floats) ----
constexpr long WS_ESUM   = 0;                         // K*D = 524288
constexpr long WS_COUNTS = 524288;                    // K
constexpr long WS_TOTAL  = 526336;                    // 1 (16B aligned)
constexpr long WS_EE     = 526400;                    // K
constexpr long WS_ZERO_FLOATS = 526400;               // zero everything before EE

// ============================================================
// Kernel 0: ee[k] = sum_d embed[k][d]^2   (one wave per code row)
// ============================================================
__global__ __launch_bounds__(256) void compute_ee_kernel(
    const float* __restrict__ embed, float* __restrict__ ee)
{
    int row  = blockIdx.x * 4 + (threadIdx.x >> 6);
    int lane = threadIdx.x & 63;
    float4 v = *(const float4*)&embed[(long)row * Dd + lane * 4];
    float s = v.x * v.x + v.y * v.y + v.z * v.z + v.w * v.w;
    #pragma unroll
    for (int off = 32; off >= 1; off >>= 1)
        s += __shfl_xor(s, off, 64);
    if (lane == 0) ee[row] = s;
}

// ============================================================
// Kernel 1: fused distance + running argmin.
// score(n,k) = ee[k] - 2 * dot(x[n], embed[k])   (same argmin as full dist)
// BM=128 rows/block, loop K in BN=128 code tiles, D in BK=32 subtiles.
// 256 threads, 8x8 micro-tile: rows r = ty+16*i, codes c = tx+16*j.
// LDS pitch 36 floats: x-reads broadcast conflict-free, e-reads 2-way (free).
// ============================================================
constexpr int BM = 128, BN = 128, BK = 32, PITCH = 36;

__global__ __launch_bounds__(256, 1) void argmin_kernel(
    const float* __restrict__ x, const float* __restrict__ embed,
    const float* __restrict__ ee, float* __restrict__ ind_out)
{
    __shared__ float xs[BM * PITCH];   // 18432 B
    __shared__ float es[BN * PITCH];   // 18432 B

    const int tid = threadIdx.x;
    const int tx = tid & 15;           // code group
    const int ty = tid >> 4;           // row group
    const long row0 = (long)blockIdx.x * BM;

    float bestv[8];
    int   besti[8];
    #pragma unroll
    for (int i = 0; i < 8; ++i) { bestv[i] = FLT_MAX; besti[i] = 0; }

    for (int ct = 0; ct < Kk / BN; ++ct) {
        float acc[8][8];
        #pragma unroll
        for (int i = 0; i < 8; ++i)
            #pragma unroll
            for (int j = 0; j < 8; ++j) acc[i][j] = 0.0f;

        for (int dt = 0; dt < Dd / BK; ++dt) {
            __syncthreads();
            // stage 128x32 of x and embed: 1024 float4 each, 4 per thread
            #pragma unroll
            for (int i = 0; i < 4; ++i) {
                int q  = tid + i * 256;     // 0..1023
                int r  = q >> 3;            // 0..127
                int dq = (q & 7) * 4;       // 0..28
                float4 xv = *(const float4*)&x[(row0 + r) * Dd + dt * BK + dq];
                *(float4*)&xs[r * PITCH + dq] = xv;
                float4 evv = *(const float4*)&embed[(long)(ct * BN + r) * Dd + dt * BK + dq];
                *(float4*)&es[r * PITCH + dq] = evv;
            }
            __syncthreads();

            #pragma unroll
            for (int dk = 0; dk < BK; dk += 4) {
                float4 xv[8], ev[8];
                #pragma unroll
                for (int i = 0; i < 8; ++i)
                    xv[i] = *(const float4*)&xs[(ty + 16 * i) * PITCH + dk];
                #pragma unroll
                for (int j = 0; j < 8; ++j)
                    ev[j] = *(const float4*)&es[(tx + 16 * j) * PITCH + dk];
                #pragma unroll
                for (int i = 0; i < 8; ++i)
                    #pragma unroll
                    for (int j = 0; j < 8; ++j)
                        acc[i][j] += xv[i].x * ev[j].x + xv[i].y * ev[j].y
                                   + xv[i].z * ev[j].z + xv[i].w * ev[j].w;
            }
        }

        // fold this code tile into the running argmin
        #pragma unroll
        for (int j = 0; j < 8; ++j) {
            int c = ct * BN + tx + 16 * j;
            float eec = ee[c];
            #pragma unroll
            for (int i = 0; i < 8; ++i) {
                float s = eec - 2.0f * acc[i][j];
                if (s < bestv[i]) { bestv[i] = s; besti[i] = c; }
            }
        }
    }

    // reduce across the 16 tx-lanes of each ty group (16 consecutive lanes)
    #pragma unroll
    for (int i = 0; i < 8; ++i) {
        float v = bestv[i]; int bi = besti[i];
        #pragma unroll
        for (int off = 8; off >= 1; off >>= 1) {
            float v2 = __shfl_xor(v, off, 16);
            int   b2 = __shfl_xor(bi, off, 16);
            if (v2 < v || (v2 == v && b2 < bi)) { v = v2; bi = b2; }
        }
        if (tx == 0) ind_out[row0 + ty + 16 * i] = (float)bi;
    }
}

// ============================================================
// Kernel 2: gather quantize rows + scatter-add embed_sum / counts.
// One 64-lane wave per x row.
// ============================================================
__global__ __launch_bounds__(256) void gather_scatter_kernel(
    const float* __restrict__ x, const float* __restrict__ embed,
    const float* __restrict__ ind_f, float* __restrict__ quant,
    float* __restrict__ embed_sum, float* __restrict__ counts)
{
    long row  = (long)blockIdx.x * 4 + (threadIdx.x >> 6);
    int  lane = threadIdx.x & 63;
    int  idx  = (int)ind_f[row];

    float4 ev = *(const float4*)&embed[(long)idx * Dd + lane * 4];
    *(float4*)&quant[row * Dd + lane * 4] = ev;

    float4 xv = *(const float4*)&x[row * Dd + lane * 4];
    float* dst = &embed_sum[(long)idx * Dd + lane * 4];
    atomicAdd(dst + 0, xv.x);
    atomicAdd(dst + 1, xv.y);
    atomicAdd(dst + 2, xv.z);
    atomicAdd(dst + 3, xv.w);
    if (lane == 0) atomicAdd(&counts[idx], 1.0f);
}

// ============================================================
// Kernel 3a: new_cluster_size + total (single block)
// ============================================================
__global__ __launch_bounds__(256) void ema_cs_kernel(
    const float* __restrict__ cs, const float* __restrict__ counts,
    float* __restrict__ ncs, float* __restrict__ total_ws)
{
    __shared__ float red[256];
    int tid = threadIdx.x;
    float s = 0.0f;
    #pragma unroll
    for (int i = 0; i < 8; ++i) {
        int k = tid + i * 256;
        float v = cs[k] * DECAY + OMD * counts[k];
        ncs[k] = v;
        s += v;
    }
    red[tid] = s;
    __syncthreads();
    #pragma unroll
    for (int off = 128; off >= 1; off >>= 1) {
        if (tid < off) red[tid] += red[tid + off];
        __syncthreads();
    }
    if (tid == 0) total_ws[0] = red[0];
}

// ============================================================
// Kernel 3b: new_embed_avg + new_embed (K*D elements, float4)
// ============================================================
__global__ __launch_bounds__(256) void ema_embed_kernel(
    const float* __restrict__ ea, const float* __restrict__ embed_sum,
    const float* __restrict__ ncs, const float* __restrict__ total_ws,
    float* __restrict__ nea, float* __restrict__ ne)
{
    long g4 = ((long)blockIdx.x * 256 + threadIdx.x);   // float4 index
    long g  = g4 * 4;
    int  k  = (int)(g >> 8);                            // /256

    float4 av = *(const float4*)&ea[g];
    float4 sv = *(const float4*)&embed_sum[g];
    float4 out_nea;
    out_nea.x = av.x * DECAY + OMD * sv.x;
    out_nea.y = av.y * DECAY + OMD * sv.y;
    out_nea.z = av.z * DECAY + OMD * sv.z;
    out_nea.w = av.w * DECAY + OMD * sv.w;
    *(float4*)&nea[g] = out_nea;

    float total = total_ws[0];
    float sm = (ncs[k] + EPSF) / (total + EPSF * (float)Kk) * total;
    float inv = 1.0f / sm;
    float4 out_ne;
    out_ne.x = out_nea.x * inv;
    out_ne.y = out_nea.y * inv;
    out_ne.z = out_nea.z * inv;
    out_ne.w = out_nea.w * inv;
    *(float4*)&ne[g] = out_ne;
}

// ============================================================
extern "C" void kernel_launch(void* const* d_in, const int* in_sizes, int n_in,
                              void* d_out, int out_size, void* d_ws, size_t ws_size,
                              hipStream_t stream)
{
    const float* x     = (const float*)d_in[0];
    const float* embed = (const float*)d_in[1];
    const float* cs    = (const float*)d_in[2];
    const float* ea    = (const float*)d_in[3];

    float* out   = (float*)d_out;
    float* quant = out + OUT_QUANT;
    float* ind_f = out + OUT_IND;
    float* ncs   = out + OUT_NCS;
    float* nea   = out + OUT_NEA;
    float* ne    = out + OUT_NE;

    float* ws        = (float*)d_ws;
    float* embed_sum = ws + WS_ESUM;
    float* counts    = ws + WS_COUNTS;
    float* total     = ws + WS_TOTAL;
    float* ee        = ws + WS_EE;

    hipMemsetAsync(d_ws, 0, WS_ZERO_FLOATS * sizeof(float), stream);

    compute_ee_kernel<<<Kk / 4, 256, 0, stream>>>(embed, ee);
    argmin_kernel<<<Nn / BM, 256, 0, stream>>>(x, embed, ee, ind_f);
    gather_scatter_kernel<<<Nn / 4, 256, 0, stream>>>(x, embed, ind_f, quant,
                                                      embed_sum, counts);
    ema_cs_kernel<<<1, 256, 0, stream>>>(cs, counts, ncs, total);
    ema_embed_kernel<<<(Kk * Dd / 4) / 256, 256, 0, stream>>>(ea, embed_sum, ncs,
                                                              total, nea, ne);
}

// Round 2
// 4484.310 us; speedup vs baseline: 2.1882x; 2.1882x over previous
//
#include <hip/hip_runtime.h>
#include <float.h>

#define DECAY 0.99f
#define OMD   0.01f
#define EPSF  1e-6f

constexpr int Bb = 8, Ss = 8192, Dd = 256, Kk = 2048;
constexpr int Nn = Bb * Ss;                 // 65536 rows

// ---- output layout (floats) ----
constexpr long OUT_QUANT = 0;                         // 16777216
constexpr long OUT_IND   = (long)Nn * Dd;             // 16777216
constexpr long OUT_NCS   = OUT_IND + Nn;              // 16842752
constexpr long OUT_NEA   = OUT_NCS + Kk;              // 16844800
constexpr long OUT_NE    = OUT_NEA + (long)Kk * Dd;   // 17369088

// ---- workspace layout (floats) ----
constexpr long WS_ESUM   = 0;                         // K*D = 524288
constexpr long WS_COUNTS = 524288;                    // K
constexpr long WS_TOTAL  = 526336;                    // 1 (16B aligned)
constexpr long WS_EE     = 526400;                    // K
constexpr long WS_ZERO_FLOATS = 526400;               // zero everything before EE

// ============================================================
// Kernel 0: ee[k] = sum_d embed[k][d]^2   (one wave per code row)
// ============================================================
__global__ __launch_bounds__(256) void compute_ee_kernel(
    const float* __restrict__ embed, float* __restrict__ ee)
{
    int row  = blockIdx.x * 4 + (threadIdx.x >> 6);
    int lane = threadIdx.x & 63;
    float4 v = *(const float4*)&embed[(long)row * Dd + lane * 4];
    float s = v.x * v.x + v.y * v.y + v.z * v.z + v.w * v.w;
    #pragma unroll
    for (int off = 32; off >= 1; off >>= 1)
        s += __shfl_xor(s, off, 64);
    if (lane == 0) ee[row] = s;
}

// ============================================================
// Kernel 1: fused distance + running argmin.
// score(n,k) = ee[k] - 2 * dot(x[n], embed[k])   (same argmin as full dist)
// BM=64 rows/block, BN=128 code tile, BK=32 d-subtile.
// 256 threads, 4x8 micro-tile: rows r = ty+16*i (i<4), codes c = tx+16*j (j<8).
// Micro-tile shrunk from 8x8 -> 4x8 after round-1 spill post-mortem
// (VGPR=256 + 23 GB scratch writes). Live set now ~110-140 VGPRs.
// LDS pitch 36: x-reads broadcast conflict-free, e-reads 2-way (free per m136).
// ============================================================
constexpr int BM = 64, BN = 128, BK = 32, PITCH = 36;

__global__ __launch_bounds__(256, 2) void argmin_kernel(
    const float* __restrict__ x, const float* __restrict__ embed,
    const float* __restrict__ ee, float* __restrict__ ind_out)
{
    __shared__ float xs[BM * PITCH];   //  9216 B
    __shared__ float es[BN * PITCH];   // 18432 B

    const int tid = threadIdx.x;
    const int tx = tid & 15;           // code group
    const int ty = tid >> 4;           // row group (0..15)
    const long row0 = (long)blockIdx.x * BM;

    float bestv[4];
    int   besti[4];
    #pragma unroll
    for (int i = 0; i < 4; ++i) { bestv[i] = FLT_MAX; besti[i] = 0; }

    for (int ct = 0; ct < Kk / BN; ++ct) {
        float acc[4][8];
        #pragma unroll
        for (int i = 0; i < 4; ++i)
            #pragma unroll
            for (int j = 0; j < 8; ++j) acc[i][j] = 0.0f;

        for (int dt = 0; dt < Dd / BK; ++dt) {
            __syncthreads();
            // stage x: 64x32 = 512 float4, 2 per thread
            #pragma unroll
            for (int i = 0; i < 2; ++i) {
                int q  = tid + i * 256;     // 0..511
                int r  = q >> 3;            // 0..63
                int dq = (q & 7) * 4;       // 0..28
                float4 xv = *(const float4*)&x[(row0 + r) * Dd + dt * BK + dq];
                *(float4*)&xs[r * PITCH + dq] = xv;
            }
            // stage embed: 128x32 = 1024 float4, 4 per thread
            #pragma unroll
            for (int i = 0; i < 4; ++i) {
                int q  = tid + i * 256;     // 0..1023
                int r  = q >> 3;            // 0..127
                int dq = (q & 7) * 4;       // 0..28
                float4 evv = *(const float4*)&embed[(long)(ct * BN + r) * Dd + dt * BK + dq];
                *(float4*)&es[r * PITCH + dq] = evv;
            }
            __syncthreads();

            #pragma unroll
            for (int dk = 0; dk < BK; dk += 4) {
                float4 xv[4];
                #pragma unroll
                for (int i = 0; i < 4; ++i)
                    xv[i] = *(const float4*)&xs[(ty + 16 * i) * PITCH + dk];
                #pragma unroll
                for (int j = 0; j < 8; ++j) {
                    float4 ev = *(const float4*)&es[(tx + 16 * j) * PITCH + dk];
                    #pragma unroll
                    for (int i = 0; i < 4; ++i)
                        acc[i][j] += xv[i].x * ev.x + xv[i].y * ev.y
                                   + xv[i].z * ev.z + xv[i].w * ev.w;
                }
            }
        }

        // fold this code tile into the running argmin
        #pragma unroll
        for (int j = 0; j < 8; ++j) {
            int c = ct * BN + tx + 16 * j;
            float eec = ee[c];
            #pragma unroll
            for (int i = 0; i < 4; ++i) {
                float s = eec - 2.0f * acc[i][j];
                if (s < bestv[i]) { bestv[i] = s; besti[i] = c; }
            }
        }
    }

    // reduce across the 16 tx-lanes of each ty group (16 consecutive lanes)
    #pragma unroll
    for (int i = 0; i < 4; ++i) {
        float v = bestv[i]; int bi = besti[i];
        #pragma unroll
        for (int off = 8; off >= 1; off >>= 1) {
            float v2 = __shfl_xor(v, off, 16);
            int   b2 = __shfl_xor(bi, off, 16);
            if (v2 < v || (v2 == v && b2 < bi)) { v = v2; bi = b2; }
        }
        if (tx == 0) ind_out[row0 + ty + 16 * i] = (float)bi;
    }
}

// ============================================================
// Kernel 2: gather quantize rows + scatter-add embed_sum / counts.
// One 64-lane wave per x row.
// ============================================================
__global__ __launch_bounds__(256) void gather_scatter_kernel(
    const float* __restrict__ x, const float* __restrict__ embed,
    const float* __restrict__ ind_f, float* __restrict__ quant,
    float* __restrict__ embed_sum, float* __restrict__ counts)
{
    long row  = (long)blockIdx.x * 4 + (threadIdx.x >> 6);
    int  lane = threadIdx.x & 63;
    int  idx  = (int)ind_f[row];

    float4 ev = *(const float4*)&embed[(long)idx * Dd + lane * 4];
    *(float4*)&quant[row * Dd + lane * 4] = ev;

    float4 xv = *(const float4*)&x[row * Dd + lane * 4];
    float* dst = &embed_sum[(long)idx * Dd + lane * 4];
    atomicAdd(dst + 0, xv.x);
    atomicAdd(dst + 1, xv.y);
    atomicAdd(dst + 2, xv.z);
    atomicAdd(dst + 3, xv.w);
    if (lane == 0) atomicAdd(&counts[idx], 1.0f);
}

// ============================================================
// Kernel 3a: new_cluster_size + total (single block)
// ============================================================
__global__ __launch_bounds__(256) void ema_cs_kernel(
    const float* __restrict__ cs, const float* __restrict__ counts,
    float* __restrict__ ncs, float* __restrict__ total_ws)
{
    __shared__ float red[256];
    int tid = threadIdx.x;
    float s = 0.0f;
    #pragma unroll
    for (int i = 0; i < 8; ++i) {
        int k = tid + i * 256;
        float v = cs[k] * DECAY + OMD * counts[k];
        ncs[k] = v;
        s += v;
    }
    red[tid] = s;
    __syncthreads();
    #pragma unroll
    for (int off = 128; off >= 1; off >>= 1) {
        if (tid < off) red[tid] += red[tid + off];
        __syncthreads();
    }
    if (tid == 0) total_ws[0] = red[0];
}

// ============================================================
// Kernel 3b: new_embed_avg + new_embed (K*D elements, float4)
// ============================================================
__global__ __launch_bounds__(256) void ema_embed_kernel(
    const float* __restrict__ ea, const float* __restrict__ embed_sum,
    const float* __restrict__ ncs, const float* __restrict__ total_ws,
    float* __restrict__ nea, float* __restrict__ ne)
{
    long g4 = ((long)blockIdx.x * 256 + threadIdx.x);   // float4 index
    long g  = g4 * 4;
    int  k  = (int)(g >> 8);                            // /256

    float4 av = *(const float4*)&ea[g];
    float4 sv = *(const float4*)&embed_sum[g];
    float4 out_nea;
    out_nea.x = av.x * DECAY + OMD * sv.x;
    out_nea.y = av.y * DECAY + OMD * sv.y;
    out_nea.z = av.z * DECAY + OMD * sv.z;
    out_nea.w = av.w * DECAY + OMD * sv.w;
    *(float4*)&nea[g] = out_nea;

    float total = total_ws[0];
    float sm = (ncs[k] + EPSF) / (total + EPSF * (float)Kk) * total;
    float inv = 1.0f / sm;
    float4 out_ne;
    out_ne.x = out_nea.x * inv;
    out_ne.y = out_nea.y * inv;
    out_ne.z = out_nea.z * inv;
    out_ne.w = out_nea.w * inv;
    *(float4*)&ne[g] = out_ne;
}

// ============================================================
extern "C" void kernel_launch(void* const* d_in, const int* in_sizes, int n_in,
                              void* d_out, int out_size, void* d_ws, size_t ws_size,
                              hipStream_t stream)
{
    const float* x     = (const float*)d_in[0];
    const float* embed = (const float*)d_in[1];
    const float* cs    = (const float*)d_in[2];
    const float* ea    = (const float*)d_in[3];

    float* out   = (float*)d_out;
    float* quant = out + OUT_QUANT;
    float* ind_f = out + OUT_IND;
    float* ncs   = out + OUT_NCS;
    float* nea   = out + OUT_NEA;
    float* ne    = out + OUT_NE;

    float* ws        = (float*)d_ws;
    float* embed_sum = ws + WS_ESUM;
    float* counts    = ws + WS_COUNTS;
    float* total     = ws + WS_TOTAL;
    float* ee        = ws + WS_EE;

    hipMemsetAsync(d_ws, 0, WS_ZERO_FLOATS * sizeof(float), stream);

    compute_ee_kernel<<<Kk / 4, 256, 0, stream>>>(embed, ee);
    argmin_kernel<<<Nn / BM, 256, 0, stream>>>(x, embed, ee, ind_f);
    gather_scatter_kernel<<<Nn / 4, 256, 0, stream>>>(x, embed, ind_f, quant,
                                                      embed_sum, counts);
    ema_cs_kernel<<<1, 256, 0, stream>>>(cs, counts, ncs, total);
    ema_embed_kernel<<<(Kk * Dd / 4) / 256, 256, 0, stream>>>(ea, embed_sum, ncs,
                                                              total, nea, ne);
}

// Round 3
// 996.383 us; speedup vs baseline: 9.8484x; 4.5006x over previous
//
#include <hip/hip_runtime.h>
#include <hip/hip_bf16.h>
#include <float.h>

#define DECAY 0.99f
#define OMD   0.01f
#define EPSF  1e-6f

constexpr int Bb = 8, Ss = 8192, Dd = 256, Kk = 2048;
constexpr int Nn = Bb * Ss;                 // 65536 rows

// ---- output layout (floats) ----
constexpr long OUT_QUANT = 0;                         // 16777216 floats
constexpr long OUT_IND   = (long)Nn * Dd;             // 16777216
constexpr long OUT_NCS   = OUT_IND + Nn;              // 16842752
constexpr long OUT_NEA   = OUT_NCS + Kk;              // 16844800
constexpr long OUT_NE    = OUT_NEA + (long)Kk * Dd;   // 17369088

// ---- workspace layout (floats) ----
constexpr long WS_ESUM   = 0;                         // K*D = 524288
constexpr long WS_COUNTS = 524288;                    // K
constexpr long WS_TOTAL  = 526336;                    // 1 (16B aligned)
constexpr long WS_EE     = 526400;                    // K
constexpr long WS_ZERO_FLOATS = 526336;               // zero embed_sum+counts

// scratch carved out of d_out (all regions are overwritten later by final
// writers; harness poisons d_out each call so nothing persists anyway):
//   quant region  [OUT_QUANT, +16777216): x_hi (16.7M bf16) + x_lo (16.7M bf16)
//   nea   region  [OUT_NEA,   +524288):   e_hi (512K bf16) + e_lo (512K bf16)
//   ne    region  [OUT_NE,    +524288):   ambiguity queue (count + row ids)

typedef __attribute__((ext_vector_type(8))) short short8;
typedef __attribute__((ext_vector_type(4))) float floatx4;

// certainty window on score scale (score = ee - 2*dot). Split-bf16 worst-case
// |approx-exact| ~ 1.6e-2; window 2*delta = 1/16 gives 4x margin. Rows with
// top2 gap <= window get an exact fp32 rescan in pass 2.
#define WINDOW 0.0625f

// ============================================================
// Kernel A: x -> x_hi(bf16), x_lo = bf16(x - x_hi)
// ============================================================
__global__ __launch_bounds__(256) void convert_x_kernel(
    const float* __restrict__ x, ushort* __restrict__ x_hi, ushort* __restrict__ x_lo)
{
    long base = ((long)blockIdx.x * 256 + threadIdx.x) * 4;
    float4 v = *(const float4*)&x[base];
    ushort4 h, l;
    float vv[4] = {v.x, v.y, v.z, v.w};
    ushort hh[4], ll[4];
    #pragma unroll
    for (int i = 0; i < 4; ++i) {
        __hip_bfloat16 hb = __float2bfloat16(vv[i]);
        float r = vv[i] - __bfloat162float(hb);
        __hip_bfloat16 lb = __float2bfloat16(r);
        hh[i] = *(ushort*)&hb; ll[i] = *(ushort*)&lb;
    }
    h.x = hh[0]; h.y = hh[1]; h.z = hh[2]; h.w = hh[3];
    l.x = ll[0]; l.y = ll[1]; l.z = ll[2]; l.w = ll[3];
    *(ushort4*)&x_hi[base] = h;
    *(ushort4*)&x_lo[base] = l;
}

// ============================================================
// Kernel B: embed -> e_hi, e_lo and ee[k] = sum_d embed[k][d]^2
// one wave per code row
// ============================================================
__global__ __launch_bounds__(256) void convert_e_kernel(
    const float* __restrict__ embed, ushort* __restrict__ e_hi,
    ushort* __restrict__ e_lo, float* __restrict__ ee)
{
    int row  = blockIdx.x * 4 + (threadIdx.x >> 6);
    int lane = threadIdx.x & 63;
    long base = (long)row * Dd + lane * 4;
    float4 v = *(const float4*)&embed[base];
    float vv[4] = {v.x, v.y, v.z, v.w};
    ushort hh[4], ll[4];
    float s = 0.0f;
    #pragma unroll
    for (int i = 0; i < 4; ++i) {
        s += vv[i] * vv[i];
        __hip_bfloat16 hb = __float2bfloat16(vv[i]);
        float r = vv[i] - __bfloat162float(hb);
        __hip_bfloat16 lb = __float2bfloat16(r);
        hh[i] = *(ushort*)&hb; ll[i] = *(ushort*)&lb;
    }
    ushort4 h; h.x = hh[0]; h.y = hh[1]; h.z = hh[2]; h.w = hh[3];
    ushort4 l; l.x = ll[0]; l.y = ll[1]; l.z = ll[2]; l.w = ll[3];
    *(ushort4*)&e_hi[base] = h;
    *(ushort4*)&e_lo[base] = l;
    #pragma unroll
    for (int off = 32; off >= 1; off >>= 1)
        s += __shfl_xor(s, off, 64);
    if (lane == 0) ee[row] = s;
}

// ============================================================
// Kernel C (pass 1): MFMA split-bf16 fused GEMM + top-2 argmin.
// Block tile 128 rows x 128 codes, 4 waves in 2x2 (wave tile 64x64).
// K' = 768 = three 256-d products: [x_hi.e_hi | x_lo.e_hi | x_hi.e_lo].
// LDS tiles row-major, pitch 56 bf16 (112 B): 16B-aligned, 2-way banks.
// mfma_f32_16x16x32_bf16: A[m=lane&15][k=quad*8+j]; C: col=lane&15,
// row=quad*4+reg (m89/m91-verified mapping).
// ============================================================
__global__ __attribute__((amdgpu_waves_per_eu(2, 2))) __launch_bounds__(256)
void pass1_kernel(
    const ushort* __restrict__ x_hi, const ushort* __restrict__ x_lo,
    const ushort* __restrict__ e_hi, const ushort* __restrict__ e_lo,
    const float* __restrict__ ee, float* __restrict__ ind_out,
    int* __restrict__ qbase)
{
    constexpr int PITCH = 56;                 // bf16 elements (112 B)
    __shared__ ushort as[128 * PITCH];        // 14336 B
    __shared__ ushort bs[128 * PITCH];        // 14336 B
    __shared__ float  redv[2][128];
    __shared__ float  red2[2][128];
    __shared__ int    redi[2][128];

    const int tid  = threadIdx.x;
    const int lane = tid & 63;
    const int quad = lane >> 4;
    const int l15  = lane & 15;
    const int w    = tid >> 6;
    const int wy   = w >> 1;                  // row half
    const int wx   = w & 1;                   // col half
    const long row0 = (long)blockIdx.x * 128;

    float bestv[16], best2v[16];
    int   besti[16];
    #pragma unroll
    for (int i = 0; i < 16; ++i) { bestv[i] = FLT_MAX; best2v[i] = FLT_MAX; besti[i] = 0; }

    for (int ct = 0; ct < Kk / 128; ++ct) {
        floatx4 acc[4][4];
        #pragma unroll
        for (int rt = 0; rt < 4; ++rt)
            #pragma unroll
            for (int jt = 0; jt < 4; ++jt)
                acc[rt][jt] = (floatx4){0.f, 0.f, 0.f, 0.f};

        for (int kt = 0; kt < 24; ++kt) {
            const int seg  = kt >> 3;
            const int kcol = (kt & 7) * 32;
            const ushort* Ap = (seg == 1) ? x_lo : x_hi;
            const ushort* Bp = (seg == 2) ? e_lo : e_hi;

            __syncthreads();
            // stage A,B tiles: 128 rows x 32 bf16 (64 B = 4 chunks of 16 B)
            #pragma unroll
            for (int i = 0; i < 2; ++i) {
                int c   = tid + i * 256;         // 0..511
                int r   = c >> 2;
                int prt = (c & 3) * 8;           // bf16 offset within row
                float4 va = *(const float4*)&Ap[(row0 + r) * Dd + kcol + prt];
                *(float4*)&as[r * PITCH + prt] = va;
                float4 vb = *(const float4*)&Bp[(long)(ct * 128 + r) * Dd + kcol + prt];
                *(float4*)&bs[r * PITCH + prt] = vb;
            }
            __syncthreads();

            short8 af[4], bf[4];
            #pragma unroll
            for (int rt = 0; rt < 4; ++rt)
                af[rt] = *(const short8*)&as[(wy * 64 + rt * 16 + l15) * PITCH + quad * 8];
            #pragma unroll
            for (int jt = 0; jt < 4; ++jt)
                bf[jt] = *(const short8*)&bs[(wx * 64 + jt * 16 + l15) * PITCH + quad * 8];
            #pragma unroll
            for (int rt = 0; rt < 4; ++rt)
                #pragma unroll
                for (int jt = 0; jt < 4; ++jt)
                    acc[rt][jt] = __builtin_amdgcn_mfma_f32_16x16x32_bf16(
                        af[rt], bf[jt], acc[rt][jt], 0, 0, 0);
        }

        // fold tile into running top-2 per row
        #pragma unroll
        for (int jt = 0; jt < 4; ++jt) {
            int c = ct * 128 + wx * 64 + jt * 16 + l15;
            float eec = ee[c];
            #pragma unroll
            for (int rt = 0; rt < 4; ++rt) {
                #pragma unroll
                for (int reg = 0; reg < 4; ++reg) {
                    float s = eec - 2.0f * acc[rt][jt][reg];
                    int slot = rt * 4 + reg;
                    if (s < bestv[slot]) {
                        best2v[slot] = bestv[slot];
                        bestv[slot] = s; besti[slot] = c;
                    } else {
                        best2v[slot] = fminf(best2v[slot], s);
                    }
                }
            }
        }
    }

    // reduce top-2 across the 16 lanes of each quad (butterfly, width 16)
    #pragma unroll
    for (int slot = 0; slot < 16; ++slot) {
        float bv = bestv[slot]; int bi = besti[slot]; float b2 = best2v[slot];
        #pragma unroll
        for (int off = 8; off >= 1; off >>= 1) {
            float ov  = __shfl_xor(bv, off, 16);
            int   oi  = __shfl_xor(bi, off, 16);
            float ov2 = __shfl_xor(b2, off, 16);
            float nm2 = fminf(fminf(b2, ov2), fmaxf(bv, ov));
            if (ov < bv) { bv = ov; bi = oi; }
            b2 = nm2;
        }
        bestv[slot] = bv; besti[slot] = bi; best2v[slot] = b2;
    }

    // cross-wave (wx halves) combine via LDS
    if (l15 == 0) {
        #pragma unroll
        for (int rt = 0; rt < 4; ++rt)
            #pragma unroll
            for (int reg = 0; reg < 4; ++reg) {
                int rloc = wy * 64 + rt * 16 + quad * 4 + reg;
                int slot = rt * 4 + reg;
                redv[wx][rloc] = bestv[slot];
                red2[wx][rloc] = best2v[slot];
                redi[wx][rloc] = besti[slot];
            }
    }
    __syncthreads();
    if (tid < 128) {
        float v0 = redv[0][tid], v1 = redv[1][tid];
        float s0 = red2[0][tid], s1 = red2[1][tid];
        float m1, m2; int mi;
        if (v0 <= v1) { m1 = v0; mi = redi[0][tid]; m2 = fminf(fminf(s0, s1), v1); }
        else          { m1 = v1; mi = redi[1][tid]; m2 = fminf(fminf(s0, s1), v0); }
        long rowAbs = row0 + tid;
        ind_out[rowAbs] = (float)mi;
        if (m2 - m1 <= WINDOW) {
            int q = atomicAdd(qbase, 1);
            qbase[1 + q] = (int)rowAbs;
        }
    }
}

// ============================================================
// Kernel D (pass 2): exact fp32 rescan of ambiguous rows.
// ============================================================
__global__ __launch_bounds__(256) void pass2_kernel(
    const float* __restrict__ x, const float* __restrict__ embed,
    const float* __restrict__ ee, const int* __restrict__ qbase,
    float* __restrict__ ind_out)
{
    __shared__ float xs[256];
    __shared__ float sv[256];
    __shared__ int   si[256];
    const int tid = threadIdx.x;
    const int count = qbase[0];

    for (int qi = blockIdx.x; qi < count; qi += gridDim.x) {
        int row = qbase[1 + qi];
        __syncthreads();
        xs[tid] = x[(long)row * Dd + tid];
        __syncthreads();
        float bv = FLT_MAX; int bi = 0;
        for (int c = tid; c < Kk; c += 256) {
            const float* er = &embed[(long)c * Dd];
            float dot = 0.0f;
            for (int d = 0; d < Dd; ++d) dot += xs[d] * er[d];
            float s = ee[c] - 2.0f * dot;
            if (s < bv) { bv = s; bi = c; }
        }
        sv[tid] = bv; si[tid] = bi;
        __syncthreads();
        for (int off = 128; off >= 1; off >>= 1) {
            if (tid < off) {
                float v2 = sv[tid + off]; int i2 = si[tid + off];
                if (v2 < sv[tid] || (v2 == sv[tid] && i2 < si[tid])) {
                    sv[tid] = v2; si[tid] = i2;
                }
            }
            __syncthreads();
        }
        if (tid == 0) ind_out[row] = (float)si[0];
    }
}

// ============================================================
// Kernel E: gather quantize rows + scatter-add embed_sum / counts.
// ============================================================
__global__ __launch_bounds__(256) void gather_scatter_kernel(
    const float* __restrict__ x, const float* __restrict__ embed,
    const float* __restrict__ ind_f, float* __restrict__ quant,
    float* __restrict__ embed_sum, float* __restrict__ counts)
{
    long row  = (long)blockIdx.x * 4 + (threadIdx.x >> 6);
    int  lane = threadIdx.x & 63;
    int  idx  = (int)ind_f[row];

    float4 ev = *(const float4*)&embed[(long)idx * Dd + lane * 4];
    *(float4*)&quant[row * Dd + lane * 4] = ev;

    float4 xv = *(const float4*)&x[row * Dd + lane * 4];
    float* dst = &embed_sum[(long)idx * Dd + lane * 4];
    atomicAdd(dst + 0, xv.x);
    atomicAdd(dst + 1, xv.y);
    atomicAdd(dst + 2, xv.z);
    atomicAdd(dst + 3, xv.w);
    if (lane == 0) atomicAdd(&counts[idx], 1.0f);
}

// ============================================================
// Kernel F: new_cluster_size + total (single block)
// ============================================================
__global__ __launch_bounds__(256) void ema_cs_kernel(
    const float* __restrict__ cs, const float* __restrict__ counts,
    float* __restrict__ ncs, float* __restrict__ total_ws)
{
    __shared__ float red[256];
    int tid = threadIdx.x;
    float s = 0.0f;
    #pragma unroll
    for (int i = 0; i < 8; ++i) {
        int k = tid + i * 256;
        float v = cs[k] * DECAY + OMD * counts[k];
        ncs[k] = v;
        s += v;
    }
    red[tid] = s;
    __syncthreads();
    #pragma unroll
    for (int off = 128; off >= 1; off >>= 1) {
        if (tid < off) red[tid] += red[tid + off];
        __syncthreads();
    }
    if (tid == 0) total_ws[0] = red[0];
}

// ============================================================
// Kernel G: new_embed_avg + new_embed
// ============================================================
__global__ __launch_bounds__(256) void ema_embed_kernel(
    const float* __restrict__ ea, const float* __restrict__ embed_sum,
    const float* __restrict__ ncs, const float* __restrict__ total_ws,
    float* __restrict__ nea, float* __restrict__ ne)
{
    long g = ((long)blockIdx.x * 256 + threadIdx.x) * 4;
    int  k = (int)(g >> 8);

    float4 av = *(const float4*)&ea[g];
    float4 sv = *(const float4*)&embed_sum[g];
    float4 out_nea;
    out_nea.x = av.x * DECAY + OMD * sv.x;
    out_nea.y = av.y * DECAY + OMD * sv.y;
    out_nea.z = av.z * DECAY + OMD * sv.z;
    out_nea.w = av.w * DECAY + OMD * sv.w;
    *(float4*)&nea[g] = out_nea;

    float total = total_ws[0];
    float sm = (ncs[k] + EPSF) / (total + EPSF * (float)Kk) * total;
    float inv = 1.0f / sm;
    float4 out_ne;
    out_ne.x = out_nea.x * inv;
    out_ne.y = out_nea.y * inv;
    out_ne.z = out_nea.z * inv;
    out_ne.w = out_nea.w * inv;
    *(float4*)&ne[g] = out_ne;
}

// ============================================================
extern "C" void kernel_launch(void* const* d_in, const int* in_sizes, int n_in,
                              void* d_out, int out_size, void* d_ws, size_t ws_size,
                              hipStream_t stream)
{
    const float* x     = (const float*)d_in[0];
    const float* embed = (const float*)d_in[1];
    const float* cs    = (const float*)d_in[2];
    const float* ea    = (const float*)d_in[3];

    float* out   = (float*)d_out;
    float* quant = out + OUT_QUANT;
    float* ind_f = out + OUT_IND;
    float* ncs   = out + OUT_NCS;
    float* nea   = out + OUT_NEA;
    float* ne    = out + OUT_NE;

    float* ws        = (float*)d_ws;
    float* embed_sum = ws + WS_ESUM;
    float* counts    = ws + WS_COUNTS;
    float* total     = ws + WS_TOTAL;
    float* ee        = ws + WS_EE;

    // scratch inside d_out (see layout notes above)
    ushort* x_hi = (ushort*)(out + OUT_QUANT);                 // 16.7M bf16
    ushort* x_lo = (ushort*)(out + OUT_QUANT + Nn * (Dd / 2)); // next 32 MB
    ushort* e_hi = (ushort*)(out + OUT_NEA);                   // 512K bf16
    ushort* e_lo = (ushort*)(out + OUT_NEA + Kk * (Dd / 2));
    int*    qb   = (int*)(out + OUT_NE);                       // count + rows

    hipMemsetAsync(d_ws, 0, WS_ZERO_FLOATS * sizeof(float), stream);
    hipMemsetAsync(qb, 0, sizeof(int), stream);

    convert_x_kernel<<<(Nn * Dd / 4) / 256, 256, 0, stream>>>(x, x_hi, x_lo);
    convert_e_kernel<<<Kk / 4, 256, 0, stream>>>(embed, e_hi, e_lo, ee);
    pass1_kernel<<<Nn / 128, 256, 0, stream>>>(x_hi, x_lo, e_hi, e_lo, ee, ind_f, qb);
    pass2_kernel<<<256, 256, 0, stream>>>(x, embed, ee, qb, ind_f);
    gather_scatter_kernel<<<Nn / 4, 256, 0, stream>>>(x, embed, ind_f, quant,
                                                      embed_sum, counts);
    ema_cs_kernel<<<1, 256, 0, stream>>>(cs, counts, ncs, total);
    ema_embed_kernel<<<(Kk * Dd / 4) / 256, 256, 0, stream>>>(ea, embed_sum, ncs,
                                                              total, nea, ne);
}

// Round 4
// 680.493 us; speedup vs baseline: 14.4200x; 1.4642x over previous
//
#include <hip/hip_runtime.h>
#include <hip/hip_bf16.h>
#include <float.h>

#define DECAY 0.99f
#define OMD   0.01f
#define EPSF  1e-6f

constexpr int Bb = 8, Ss = 8192, Dd = 256, Kk = 2048;
constexpr int Nn = Bb * Ss;                 // 65536 rows

// ---- output layout (floats) ----
constexpr long OUT_QUANT = 0;                         // 16777216 floats
constexpr long OUT_IND   = (long)Nn * Dd;             // 16777216
constexpr long OUT_NCS   = OUT_IND + Nn;              // 16842752
constexpr long OUT_NEA   = OUT_NCS + Kk;              // 16844800
constexpr long OUT_NE    = OUT_NEA + (long)Kk * Dd;   // 17369088

// ---- workspace layout (floats) ----
constexpr long WS_COUNTS = 0;                         // K
constexpr long WS_TOTAL  = 2048;                      // 1
constexpr long WS_EE     = 2112;                      // K
constexpr long WS_BIG    = 4160;                      // embed_sum (atomic path)
                                                      // or 8 partials (ws path)
constexpr int  PARTS     = 8;                         // strip split for segsum

// scratch carved out of d_out (regions overwritten later by final writers):
//   quant region: x_hi (16.7M bf16) + x_lo (16.7M bf16)
//   nea   region: e_hi + e_lo (bf16)
//   ne    region: ambiguity queue (count + row ids)

typedef __attribute__((ext_vector_type(8))) short short8;
typedef __attribute__((ext_vector_type(4))) float floatx4;

// split-bf16 certainty window (see round-2 notes): rows whose approx top-2
// gap <= WINDOW get an exact fp32 rescan in pass 2.
#define WINDOW 0.0625f

// ============================================================
// Kernel A: x -> x_hi(bf16), x_lo = bf16(x - x_hi)
// ============================================================
__global__ __launch_bounds__(256) void convert_x_kernel(
    const float* __restrict__ x, ushort* __restrict__ x_hi, ushort* __restrict__ x_lo)
{
    long base = ((long)blockIdx.x * 256 + threadIdx.x) * 4;
    float4 v = *(const float4*)&x[base];
    float vv[4] = {v.x, v.y, v.z, v.w};
    ushort hh[4], ll[4];
    #pragma unroll
    for (int i = 0; i < 4; ++i) {
        __hip_bfloat16 hb = __float2bfloat16(vv[i]);
        float r = vv[i] - __bfloat162float(hb);
        __hip_bfloat16 lb = __float2bfloat16(r);
        hh[i] = *(ushort*)&hb; ll[i] = *(ushort*)&lb;
    }
    ushort4 h; h.x = hh[0]; h.y = hh[1]; h.z = hh[2]; h.w = hh[3];
    ushort4 l; l.x = ll[0]; l.y = ll[1]; l.z = ll[2]; l.w = ll[3];
    *(ushort4*)&x_hi[base] = h;
    *(ushort4*)&x_lo[base] = l;
}

// ============================================================
// Kernel B: embed -> e_hi, e_lo and ee[k] = sum_d embed[k][d]^2
// ============================================================
__global__ __launch_bounds__(256) void convert_e_kernel(
    const float* __restrict__ embed, ushort* __restrict__ e_hi,
    ushort* __restrict__ e_lo, float* __restrict__ ee)
{
    int row  = blockIdx.x * 4 + (threadIdx.x >> 6);
    int lane = threadIdx.x & 63;
    long base = (long)row * Dd + lane * 4;
    float4 v = *(const float4*)&embed[base];
    float vv[4] = {v.x, v.y, v.z, v.w};
    ushort hh[4], ll[4];
    float s = 0.0f;
    #pragma unroll
    for (int i = 0; i < 4; ++i) {
        s += vv[i] * vv[i];
        __hip_bfloat16 hb = __float2bfloat16(vv[i]);
        float r = vv[i] - __bfloat162float(hb);
        __hip_bfloat16 lb = __float2bfloat16(r);
        hh[i] = *(ushort*)&hb; ll[i] = *(ushort*)&lb;
    }
    ushort4 h; h.x = hh[0]; h.y = hh[1]; h.z = hh[2]; h.w = hh[3];
    ushort4 l; l.x = ll[0]; l.y = ll[1]; l.z = ll[2]; l.w = ll[3];
    *(ushort4*)&e_hi[base] = h;
    *(ushort4*)&e_lo[base] = l;
    #pragma unroll
    for (int off = 32; off >= 1; off >>= 1)
        s += __shfl_xor(s, off, 64);
    if (lane == 0) ee[row] = s;
}

// ============================================================
// Kernel C (pass 1): MFMA split-bf16 fused GEMM + top-2 argmin.
// (unchanged from round 3 — see comments there)
// ============================================================
__global__ __attribute__((amdgpu_waves_per_eu(2, 2))) __launch_bounds__(256)
void pass1_kernel(
    const ushort* __restrict__ x_hi, const ushort* __restrict__ x_lo,
    const ushort* __restrict__ e_hi, const ushort* __restrict__ e_lo,
    const float* __restrict__ ee, float* __restrict__ ind_out,
    int* __restrict__ qbase)
{
    constexpr int PITCH = 56;                 // bf16 elements (112 B)
    __shared__ ushort as[128 * PITCH];
    __shared__ ushort bs[128 * PITCH];
    __shared__ float  redv[2][128];
    __shared__ float  red2[2][128];
    __shared__ int    redi[2][128];

    const int tid  = threadIdx.x;
    const int lane = tid & 63;
    const int quad = lane >> 4;
    const int l15  = lane & 15;
    const int w    = tid >> 6;
    const int wy   = w >> 1;
    const int wx   = w & 1;
    const long row0 = (long)blockIdx.x * 128;

    float bestv[16], best2v[16];
    int   besti[16];
    #pragma unroll
    for (int i = 0; i < 16; ++i) { bestv[i] = FLT_MAX; best2v[i] = FLT_MAX; besti[i] = 0; }

    for (int ct = 0; ct < Kk / 128; ++ct) {
        floatx4 acc[4][4];
        #pragma unroll
        for (int rt = 0; rt < 4; ++rt)
            #pragma unroll
            for (int jt = 0; jt < 4; ++jt)
                acc[rt][jt] = (floatx4){0.f, 0.f, 0.f, 0.f};

        for (int kt = 0; kt < 24; ++kt) {
            const int seg  = kt >> 3;
            const int kcol = (kt & 7) * 32;
            const ushort* Ap = (seg == 1) ? x_lo : x_hi;
            const ushort* Bp = (seg == 2) ? e_lo : e_hi;

            __syncthreads();
            #pragma unroll
            for (int i = 0; i < 2; ++i) {
                int c   = tid + i * 256;
                int r   = c >> 2;
                int prt = (c & 3) * 8;
                float4 va = *(const float4*)&Ap[(row0 + r) * Dd + kcol + prt];
                *(float4*)&as[r * PITCH + prt] = va;
                float4 vb = *(const float4*)&Bp[(long)(ct * 128 + r) * Dd + kcol + prt];
                *(float4*)&bs[r * PITCH + prt] = vb;
            }
            __syncthreads();

            short8 af[4], bf[4];
            #pragma unroll
            for (int rt = 0; rt < 4; ++rt)
                af[rt] = *(const short8*)&as[(wy * 64 + rt * 16 + l15) * PITCH + quad * 8];
            #pragma unroll
            for (int jt = 0; jt < 4; ++jt)
                bf[jt] = *(const short8*)&bs[(wx * 64 + jt * 16 + l15) * PITCH + quad * 8];
            #pragma unroll
            for (int rt = 0; rt < 4; ++rt)
                #pragma unroll
                for (int jt = 0; jt < 4; ++jt)
                    acc[rt][jt] = __builtin_amdgcn_mfma_f32_16x16x32_bf16(
                        af[rt], bf[jt], acc[rt][jt], 0, 0, 0);
        }

        #pragma unroll
        for (int jt = 0; jt < 4; ++jt) {
            int c = ct * 128 + wx * 64 + jt * 16 + l15;
            float eec = ee[c];
            #pragma unroll
            for (int rt = 0; rt < 4; ++rt) {
                #pragma unroll
                for (int reg = 0; reg < 4; ++reg) {
                    float s = eec - 2.0f * acc[rt][jt][reg];
                    int slot = rt * 4 + reg;
                    if (s < bestv[slot]) {
                        best2v[slot] = bestv[slot];
                        bestv[slot] = s; besti[slot] = c;
                    } else {
                        best2v[slot] = fminf(best2v[slot], s);
                    }
                }
            }
        }
    }

    #pragma unroll
    for (int slot = 0; slot < 16; ++slot) {
        float bv = bestv[slot]; int bi = besti[slot]; float b2 = best2v[slot];
        #pragma unroll
        for (int off = 8; off >= 1; off >>= 1) {
            float ov  = __shfl_xor(bv, off, 16);
            int   oi  = __shfl_xor(bi, off, 16);
            float ov2 = __shfl_xor(b2, off, 16);
            float nm2 = fminf(fminf(b2, ov2), fmaxf(bv, ov));
            if (ov < bv) { bv = ov; bi = oi; }
            b2 = nm2;
        }
        bestv[slot] = bv; besti[slot] = bi; best2v[slot] = b2;
    }

    if (l15 == 0) {
        #pragma unroll
        for (int rt = 0; rt < 4; ++rt)
            #pragma unroll
            for (int reg = 0; reg < 4; ++reg) {
                int rloc = wy * 64 + rt * 16 + quad * 4 + reg;
                int slot = rt * 4 + reg;
                redv[wx][rloc] = bestv[slot];
                red2[wx][rloc] = best2v[slot];
                redi[wx][rloc] = besti[slot];
            }
    }
    __syncthreads();
    if (tid < 128) {
        float v0 = redv[0][tid], v1 = redv[1][tid];
        float s0 = red2[0][tid], s1 = red2[1][tid];
        float m1, m2; int mi;
        if (v0 <= v1) { m1 = v0; mi = redi[0][tid]; m2 = fminf(fminf(s0, s1), v1); }
        else          { m1 = v1; mi = redi[1][tid]; m2 = fminf(fminf(s0, s1), v0); }
        long rowAbs = row0 + tid;
        ind_out[rowAbs] = (float)mi;
        if (m2 - m1 <= WINDOW) {
            int q = atomicAdd(qbase, 1);
            qbase[1 + q] = (int)rowAbs;
        }
    }
}

// ============================================================
// Kernel D (pass 2): exact fp32 rescan of ambiguous rows.
// ============================================================
__global__ __launch_bounds__(256) void pass2_kernel(
    const float* __restrict__ x, const float* __restrict__ embed,
    const float* __restrict__ ee, const int* __restrict__ qbase,
    float* __restrict__ ind_out)
{
    __shared__ float xs[256];
    __shared__ float sv[256];
    __shared__ int   si[256];
    const int tid = threadIdx.x;
    const int count = qbase[0];

    for (int qi = blockIdx.x; qi < count; qi += gridDim.x) {
        int row = qbase[1 + qi];
        __syncthreads();
        xs[tid] = x[(long)row * Dd + tid];
        __syncthreads();
        float bv = FLT_MAX; int bi = 0;
        for (int c = tid; c < Kk; c += 256) {
            const float* er = &embed[(long)c * Dd];
            float dot = 0.0f;
            for (int d = 0; d < Dd; ++d) dot += xs[d] * er[d];
            float s = ee[c] - 2.0f * dot;
            if (s < bv) { bv = s; bi = c; }
        }
        sv[tid] = bv; si[tid] = bi;
        __syncthreads();
        for (int off = 128; off >= 1; off >>= 1) {
            if (tid < off) {
                float v2 = sv[tid + off]; int i2 = si[tid + off];
                if (v2 < sv[tid] || (v2 == sv[tid] && i2 < si[tid])) {
                    sv[tid] = v2; si[tid] = i2;
                }
            }
            __syncthreads();
        }
        if (tid == 0) ind_out[row] = (float)si[0];
    }
}

// ============================================================
// Kernel E: quantize gather (pure BW, no atomics). One wave per row.
// ============================================================
__global__ __launch_bounds__(256) void quant_gather_kernel(
    const float* __restrict__ embed, const float* __restrict__ ind_f,
    float* __restrict__ quant)
{
    long row  = (long)blockIdx.x * 4 + (threadIdx.x >> 6);
    int  lane = threadIdx.x & 63;
    int  idx  = (int)ind_f[row];
    float4 ev = *(const float4*)&embed[(long)idx * Dd + lane * 4];
    *(float4*)&quant[row * Dd + lane * 4] = ev;
}

// ============================================================
// Kernel F: pull-based segmented sum. Block (k, s): scan strip s of ind,
// ballot-match code k, accumulate matching x rows in registers.
// No data atomics (ws-partials path) or uniform <=8-per-addr atomics.
// Also produces counts[k] from ballot popcounts.
// ============================================================
template <int USE_ATOMIC>
__global__ __launch_bounds__(256) void segsum_kernel(
    const float* __restrict__ x, const float* __restrict__ ind_f,
    float* __restrict__ dst, float* __restrict__ counts)
{
    __shared__ float part[4][256];
    __shared__ float cnt_l[4];
    const int tid  = threadIdx.x;
    const int w    = tid >> 6;
    const int lane = tid & 63;
    const int k    = blockIdx.x >> 3;          // PARTS=8
    const int s    = blockIdx.x & 7;

    constexpr int STRIP = Nn / PARTS;          // 8192 rows
    constexpr int WAVE_ROWS = STRIP / 4;       // 2048 rows per wave
    const int base0 = s * STRIP + w * WAVE_ROWS;

    float4 acc = {0.f, 0.f, 0.f, 0.f};
    int cnt = 0;
    for (int win = 0; win < WAVE_ROWS; win += 64) {
        int idx = (int)ind_f[base0 + win + lane];
        unsigned long long m = __ballot(idx == k);
        cnt += __popcll(m);
        while (m) {
            int l = __ffsll((unsigned long long)m) - 1;
            m &= m - 1;
            long row = base0 + win + l;
            float4 v = *(const float4*)&x[row * Dd + lane * 4];
            acc.x += v.x; acc.y += v.y; acc.z += v.z; acc.w += v.w;
        }
    }
    *(float4*)&part[w][lane * 4] = acc;
    if (lane == 0) cnt_l[w] = (float)cnt;
    __syncthreads();
    float sum = part[0][tid] + part[1][tid] + part[2][tid] + part[3][tid];
    if (USE_ATOMIC) {
        if (sum != 0.0f) atomicAdd(&dst[(long)k * Dd + tid], sum);
    } else {
        dst[((long)s * Kk + k) * Dd + tid] = sum;
    }
    if (tid == 0)
        atomicAdd(&counts[k], cnt_l[0] + cnt_l[1] + cnt_l[2] + cnt_l[3]);
}

// ============================================================
// Kernel G: new_cluster_size + total (single block)
// ============================================================
__global__ __launch_bounds__(256) void ema_cs_kernel(
    const float* __restrict__ cs, const float* __restrict__ counts,
    float* __restrict__ ncs, float* __restrict__ total_ws)
{
    __shared__ float red[256];
    int tid = threadIdx.x;
    float s = 0.0f;
    #pragma unroll
    for (int i = 0; i < 8; ++i) {
        int k = tid + i * 256;
        float v = cs[k] * DECAY + OMD * counts[k];
        ncs[k] = v;
        s += v;
    }
    red[tid] = s;
    __syncthreads();
    #pragma unroll
    for (int off = 128; off >= 1; off >>= 1) {
        if (tid < off) red[tid] += red[tid + off];
        __syncthreads();
    }
    if (tid == 0) total_ws[0] = red[0];
}

// ============================================================
// Kernel H: combine partials -> embed_sum; nea; ne.
// nparts = PARTS (ws path) or 1 (atomic path, partials == embed_sum).
// ============================================================
__global__ __launch_bounds__(256) void nea_ne_kernel(
    const float* __restrict__ ea, const float* __restrict__ partials,
    int nparts, const float* __restrict__ ncs, const float* __restrict__ total_ws,
    float* __restrict__ nea, float* __restrict__ ne)
{
    long g = ((long)blockIdx.x * 256 + threadIdx.x) * 4;
    int  k = (int)(g >> 8);
    int  d = (int)(g & 255);

    float4 sv = {0.f, 0.f, 0.f, 0.f};
    for (int p = 0; p < nparts; ++p) {
        float4 pv = *(const float4*)&partials[((long)p * Kk + k) * Dd + d];
        sv.x += pv.x; sv.y += pv.y; sv.z += pv.z; sv.w += pv.w;
    }

    float4 av = *(const float4*)&ea[g];
    float4 out_nea;
    out_nea.x = av.x * DECAY + OMD * sv.x;
    out_nea.y = av.y * DECAY + OMD * sv.y;
    out_nea.z = av.z * DECAY + OMD * sv.z;
    out_nea.w = av.w * DECAY + OMD * sv.w;
    *(float4*)&nea[g] = out_nea;

    float total = total_ws[0];
    float sm = (ncs[k] + EPSF) / (total + EPSF * (float)Kk) * total;
    float inv = 1.0f / sm;
    float4 out_ne;
    out_ne.x = out_nea.x * inv;
    out_ne.y = out_nea.y * inv;
    out_ne.z = out_nea.z * inv;
    out_ne.w = out_nea.w * inv;
    *(float4*)&ne[g] = out_ne;
}

// ============================================================
extern "C" void kernel_launch(void* const* d_in, const int* in_sizes, int n_in,
                              void* d_out, int out_size, void* d_ws, size_t ws_size,
                              hipStream_t stream)
{
    const float* x     = (const float*)d_in[0];
    const float* embed = (const float*)d_in[1];
    const float* cs    = (const float*)d_in[2];
    const float* ea    = (const float*)d_in[3];

    float* out   = (float*)d_out;
    float* quant = out + OUT_QUANT;
    float* ind_f = out + OUT_IND;
    float* ncs   = out + OUT_NCS;
    float* nea   = out + OUT_NEA;
    float* ne    = out + OUT_NE;

    float* ws     = (float*)d_ws;
    float* counts = ws + WS_COUNTS;
    float* total  = ws + WS_TOTAL;
    float* ee     = ws + WS_EE;
    float* big    = ws + WS_BIG;     // embed_sum (atomic) or partials (ws path)

    // scratch inside d_out
    ushort* x_hi = (ushort*)(out + OUT_QUANT);
    ushort* x_lo = (ushort*)(out + OUT_QUANT + Nn * (Dd / 2));
    ushort* e_hi = (ushort*)(out + OUT_NEA);
    ushort* e_lo = (ushort*)(out + OUT_NEA + Kk * (Dd / 2));
    int*    qb   = (int*)(out + OUT_NE);

    const size_t need_partials =
        (size_t)(WS_BIG + (long)PARTS * Kk * Dd) * sizeof(float) + 1024;
    const bool use_ws_partials = ws_size >= need_partials;

    hipMemsetAsync(counts, 0, Kk * sizeof(float), stream);
    hipMemsetAsync(qb, 0, sizeof(int), stream);
    if (!use_ws_partials)
        hipMemsetAsync(big, 0, (size_t)Kk * Dd * sizeof(float), stream);

    convert_x_kernel<<<(Nn * Dd / 4) / 256, 256, 0, stream>>>(x, x_hi, x_lo);
    convert_e_kernel<<<Kk / 4, 256, 0, stream>>>(embed, e_hi, e_lo, ee);
    pass1_kernel<<<Nn / 128, 256, 0, stream>>>(x_hi, x_lo, e_hi, e_lo, ee, ind_f, qb);
    pass2_kernel<<<256, 256, 0, stream>>>(x, embed, ee, qb, ind_f);
    quant_gather_kernel<<<Nn / 4, 256, 0, stream>>>(embed, ind_f, quant);
    if (use_ws_partials)
        segsum_kernel<0><<<Kk * PARTS, 256, 0, stream>>>(x, ind_f, big, counts);
    else
        segsum_kernel<1><<<Kk * PARTS, 256, 0, stream>>>(x, ind_f, big, counts);
    ema_cs_kernel<<<1, 256, 0, stream>>>(cs, counts, ncs, total);
    nea_ne_kernel<<<(Kk * Dd / 4) / 256, 256, 0, stream>>>(
        ea, big, use_ws_partials ? PARTS : 1, ncs, total, nea, ne);
}